// Round 3
// baseline (820.371 us; speedup 1.0000x reference)
//
#include <hip/hip_runtime.h>
#include <hip/hip_bf16.h>
#include <math.h>

#define BATCH 16
#define SEQ   512
#define DC    1024
#define DP    64
#define NT    8
#define DH    4096
#define NTOK  (BATCH*SEQ)   // 8192

#define BM 128
#define BN 128
#define BK 64
#define SMEM_BYTES (BM*BK*2*2 + 512)   // As 16K + Bs 16K + toks 512 = 33280 B

typedef __attribute__((ext_vector_type(8))) short short8;        // 8 bf16
typedef __attribute__((ext_vector_type(4))) float floatx4;       // MFMA acc
typedef __attribute__((ext_vector_type(8))) unsigned short ushort8v;

__device__ __forceinline__ unsigned short f2bf(float f) {
  union { float f; unsigned u; } v; v.f = f;
  unsigned r = v.u + 0x7FFFu + ((v.u >> 16) & 1u);   // RNE
  return (unsigned short)(r >> 16);
}

__device__ __forceinline__ void gl_lds16(const void* g, void* l) {
  __builtin_amdgcn_global_load_lds(
      (__attribute__((address_space(1))) void*)g,
      (__attribute__((address_space(3))) void*)l, 16, 0, 0);
}

// ---------------- routing body: one wave per token ----------------
__device__ __forceinline__ void route_body(
    int rb, const float* __restrict__ x, const float* __restrict__ pe,
    const float* __restrict__ pwp, const float* __restrict__ cwp,
    const float* __restrict__ psig, const float* __restrict__ csig,
    int* __restrict__ counts, int* __restrict__ list,
    unsigned short* __restrict__ xb) {
  int wid  = threadIdx.x >> 6;
  int lane = threadIdx.x & 63;
  int token = rb * 4 + wid;
  int s = token & (SEQ - 1);

  float pwr = 1.f / (1.f + expf(-pwp[0]));
  float cwr = 1.f / (1.f + expf(-cwp[0]));
  float tot = pwr + cwr;
  float pw = pwr / tot, cw = cwr / tot;

  float acc[NT];
#pragma unroll
  for (int t = 0; t < NT; t++) acc[t] = 0.f;

  float a0 = pw * pe[s * DP + lane];
#pragma unroll
  for (int t = 0; t < NT; t++) {
    float v = psig[t * DP + lane];
    float sg = (v > 0.f) ? 1.f : ((v < 0.f) ? -1.f : 0.f);
    acc[t] = fmaf(a0, sg, acc[t]);
  }

  const float* xrow = x + (size_t)token * DC;
  unsigned short* xbrow = xb + (size_t)token * DC;
#pragma unroll 4
  for (int i = 0; i < DC / 64; i++) {
    int c = lane + i * 64;
    float xv = xrow[c];
    xbrow[c] = f2bf(xv);
    float a = cw * xv;
#pragma unroll
    for (int t = 0; t < NT; t++) {
      float v = csig[t * DC + c];
      float sg = (v > 0.f) ? 1.f : ((v < 0.f) ? -1.f : 0.f);
      acc[t] = fmaf(a, sg, acc[t]);
    }
  }

#pragma unroll
  for (int off = 32; off >= 1; off >>= 1)
#pragma unroll
    for (int t = 0; t < NT; t++) acc[t] += __shfl_xor(acc[t], off);

  if (lane == 0) {
    int best = 0; float bv = acc[0];
#pragma unroll
    for (int t = 1; t < NT; t++)
      if (acc[t] > bv) { bv = acc[t]; best = t; }
    int slot = atomicAdd(&counts[best], 1);
    list[best * NTOK + slot] = token;
  }
}

// ------- transpose tile body: in [AR][AC] fp32 -> out [AC][AR] bf16 ----------
__device__ __forceinline__ void transpose_tile(
    const float* __restrict__ in_t, unsigned short* __restrict__ out_t,
    int AR, int AC, int bx, int by, char* smem) {
  unsigned short* tile = (unsigned short*)smem;  // 64*65 ushorts = 8320 B
  int x0 = bx * 64, y0 = by * 64;
  int tid = threadIdx.x;
  int ry = tid >> 2, cx = (tid & 3) * 16;
  const float* src = in_t + (size_t)(y0 + ry) * AC + x0 + cx;
  float4 v0 = *(const float4*)(src);
  float4 v1 = *(const float4*)(src + 4);
  float4 v2 = *(const float4*)(src + 8);
  float4 v3 = *(const float4*)(src + 12);
  unsigned short* trow = &tile[ry * 65 + cx];
  trow[0]  = f2bf(v0.x); trow[1]  = f2bf(v0.y); trow[2]  = f2bf(v0.z); trow[3]  = f2bf(v0.w);
  trow[4]  = f2bf(v1.x); trow[5]  = f2bf(v1.y); trow[6]  = f2bf(v1.z); trow[7]  = f2bf(v1.w);
  trow[8]  = f2bf(v2.x); trow[9]  = f2bf(v2.y); trow[10] = f2bf(v2.z); trow[11] = f2bf(v2.w);
  trow[12] = f2bf(v3.x); trow[13] = f2bf(v3.y); trow[14] = f2bf(v3.z); trow[15] = f2bf(v3.w);
  __syncthreads();
  int rx = tid >> 2, cy = (tid & 3) * 16;
  ushort8v o0, o1;
#pragma unroll
  for (int j = 0; j < 8; j++) o0[j] = tile[(cy + j) * 65 + rx];
#pragma unroll
  for (int j = 0; j < 8; j++) o1[j] = tile[(cy + 8 + j) * 65 + rx];
  size_t ob = (size_t)(x0 + rx) * AR + y0 + cy;
  *(ushort8v*)&out_t[ob]     = o0;
  *(ushort8v*)&out_t[ob + 8] = o1;
}

// ---------------- gathered GEMM core, BK=64, async LDS staging ---------------
template<int K, int N, bool GELU, bool ATOMIC>
__device__ __forceinline__ void gemm_core(
    const unsigned short* __restrict__ A, const unsigned short* __restrict__ BTt,
    const float* __restrict__ biasT, const int* __restrict__ listT,
    int count, int base, int j0, int kstart, int kiters, int addbias,
    char* smem, unsigned short* __restrict__ Hout, float* __restrict__ Fout) {
  unsigned short* As = (unsigned short*)smem;        // [BM][BK]
  unsigned short* Bs = As + BM * BK;                 // [BN][BK]
  int* toks = (int*)(smem + BM * BK * 2 * 2);

  int tid = threadIdx.x;
  if (tid < BM) {
    int slot = base + tid;
    toks[tid] = (slot < count) ? listT[slot] : -1;
  }
  __syncthreads();

  int w = tid >> 6, lane = tid & 63;
  int lrow = lane >> 3;        // row within 8-row segment
  int pch  = lane & 7;         // physical 16B chunk
  int lch  = pch ^ lrow;       // logical k-chunk (XOR swizzle)

  const unsigned short* srcA[4];
  const unsigned short* srcB[4];
  unsigned short* dstA[4];
  unsigned short* dstB[4];
#pragma unroll
  for (int i = 0; i < 4; i++) {
    int s = w * 4 + i;               // segment 0..15 (8 rows, 1 KB)
    int r = s * 8 + lrow;
    int tk = toks[r]; if (tk < 0) tk = 0;
    srcA[i] = A + (size_t)tk * K + kstart + lch * 8;
    srcB[i] = BTt + (size_t)(j0 + r) * K + kstart + lch * 8;
    dstA[i] = As + s * 512;          // wave-uniform base; HW adds lane*16B
    dstB[i] = Bs + s * 512;
  }

  int wm = (w & 1) * 64, wn = (w >> 1) * 64;
  int quad = lane >> 4, l15 = lane & 15;
  int l7 = l15 & 7;

  floatx4 acc[4][4];
#pragma unroll
  for (int mi = 0; mi < 4; mi++)
#pragma unroll
    for (int ni = 0; ni < 4; ni++) acc[mi][ni] = (floatx4){0.f, 0.f, 0.f, 0.f};

  for (int kt = 0; kt < kiters; kt++) {
#pragma unroll
    for (int i = 0; i < 4; i++) gl_lds16(srcA[i], dstA[i]);
#pragma unroll
    for (int i = 0; i < 4; i++) gl_lds16(srcB[i], dstB[i]);
#pragma unroll
    for (int i = 0; i < 4; i++) { srcA[i] += BK; srcB[i] += BK; }
    __syncthreads();

#pragma unroll
    for (int t2 = 0; t2 < 2; t2++) {
      short8 a[4], b[4];
#pragma unroll
      for (int mi = 0; mi < 4; mi++) {
        int m = wm + mi * 16 + l15;
        int p = (t2 * 4 + quad) ^ l7;
        a[mi] = *(const short8*)&As[m * BK + p * 8];
      }
#pragma unroll
      for (int ni = 0; ni < 4; ni++) {
        int n = wn + ni * 16 + l15;
        int p = (t2 * 4 + quad) ^ l7;
        b[ni] = *(const short8*)&Bs[n * BK + p * 8];
      }
#pragma unroll
      for (int mi = 0; mi < 4; mi++)
#pragma unroll
        for (int ni = 0; ni < 4; ni++)
          acc[mi][ni] = __builtin_amdgcn_mfma_f32_16x16x32_bf16(a[mi], b[ni], acc[mi][ni], 0, 0, 0);
    }
    __syncthreads();
  }

#pragma unroll
  for (int ni = 0; ni < 4; ni++) {
    int n = j0 + wn + ni * 16 + l15;
    float bv = addbias ? biasT[n] : 0.f;
#pragma unroll
    for (int mi = 0; mi < 4; mi++) {
      int mb = wm + mi * 16 + quad * 4;
#pragma unroll
      for (int r = 0; r < 4; r++) {
        int tok = toks[mb + r];
        if (tok >= 0) {
          float v = acc[mi][ni][r] + bv;
          if (GELU) {
            v = 0.5f * v * (1.f + erff(v * 0.70710678118654752f));
            Hout[(size_t)tok * N + n] = f2bf(v);
          } else if (ATOMIC) {
            atomicAdd(&Fout[(size_t)tok * N + n], v);
          } else {
            Fout[(size_t)tok * N + n] = v;
          }
        }
      }
    }
  }
}

// ---------------- launch 1: transpose W1 + route (independent) --------------
__global__ __launch_bounds__(256) void prep_kernel(
    const float* __restrict__ x, const float* __restrict__ pe,
    const float* __restrict__ pwp, const float* __restrict__ cwp,
    const float* __restrict__ psig, const float* __restrict__ csig,
    int* __restrict__ counts, int* __restrict__ list,
    unsigned short* __restrict__ xb,
    const float* __restrict__ W1, unsigned short* __restrict__ W1T) {
  __shared__ __align__(16) char smem[64 * 65 * 2];
  int z = blockIdx.z;
  if (z < NT) {
    // W1 [DC][DH] -> W1T [DH][DC]; x over DH/64=64, y over DC/64=16
    transpose_tile(W1 + (size_t)z * DC * DH, W1T + (size_t)z * DC * DH,
                   DC, DH, blockIdx.x, blockIdx.y, smem);
  } else {
    int rb = (z - NT) * 1024 + blockIdx.y * 64 + blockIdx.x;   // 0..2047
    route_body(rb, x, pe, pwp, cwp, psig, csig, counts, list, xb);
  }
}

// ---------------- launch 2: gemm1 (+ optional fused transpose W2) -----------
__global__ __launch_bounds__(256) void gemm1_kernel(
    const unsigned short* __restrict__ xb, const unsigned short* __restrict__ W1T,
    const float* __restrict__ b1, const int* __restrict__ counts,
    const int* __restrict__ list, unsigned short* __restrict__ H,
    const float* __restrict__ W2, unsigned short* __restrict__ W2T) {
  __shared__ __align__(16) char smem[SMEM_BYTES];
  int z = blockIdx.z;
  if (z < NT) {
    int t = z;
    int count = counts[t];
    int base = blockIdx.y * BM;
    if (base >= count) return;
    gemm_core<DC, DH, true, false>(xb, W1T + (size_t)t * DH * DC, b1 + t * DH,
                                   list + t * NTOK, count, base, blockIdx.x * BN,
                                   0, DC / BK, 1, smem, H, nullptr);
  } else {
    if (W2T == nullptr || blockIdx.x >= 16) return;
    int t = z - NT;
    // W2 [DH][DC] -> W2T [DC][DH]; x over DC/64=16, y over DH/64=64
    transpose_tile(W2 + (size_t)t * DH * DC, W2T + (size_t)t * DH * DC,
                   DH, DC, blockIdx.x, blockIdx.y, smem);
  }
}

// standalone transpose W2 (non-overlap workspace path)
__global__ __launch_bounds__(256) void t2_kernel(
    const float* __restrict__ W2, unsigned short* __restrict__ W2T) {
  __shared__ __align__(16) char smem[64 * 65 * 2];
  int t = blockIdx.z;
  transpose_tile(W2 + (size_t)t * DH * DC, W2T + (size_t)t * DH * DC,
                 DH, DC, blockIdx.x, blockIdx.y, smem);
}

// ---------------- launch 3: gemm2, split-K x2, atomic combine ---------------
__global__ __launch_bounds__(256) void gemm2_kernel(
    const unsigned short* __restrict__ H, const unsigned short* __restrict__ W2T,
    const float* __restrict__ b2, const int* __restrict__ counts,
    const int* __restrict__ list, float* __restrict__ out) {
  __shared__ __align__(16) char smem[SMEM_BYTES];
  int z = blockIdx.z;
  int t = z >> 1, ks = z & 1;
  int count = counts[t];
  int base = blockIdx.y * BM;
  if (base >= count) return;
  gemm_core<DH, DC, false, true>(H, W2T + (size_t)t * DC * DH, b2 + t * DC,
                                 list + t * NTOK, count, base, blockIdx.x * BN,
                                 ks * (DH / 2), (DH / 2) / BK, ks == 0,
                                 smem, nullptr, out);
}

extern "C" void kernel_launch(void* const* d_in, const int* in_sizes, int n_in,
                              void* d_out, int out_size, void* d_ws, size_t ws_size,
                              hipStream_t stream) {
  const float* x        = (const float*)d_in[0];
  const float* pe       = (const float*)d_in[1];
  const float* pwp      = (const float*)d_in[2];
  const float* cwp      = (const float*)d_in[3];
  const float* psig     = (const float*)d_in[4];
  const float* csig     = (const float*)d_in[5];
  const float* W1       = (const float*)d_in[6];
  const float* b1       = (const float*)d_in[7];
  const float* W2       = (const float*)d_in[8];
  const float* b2       = (const float*)d_in[9];
  float* out = (float*)d_out;

  char* ws = (char*)d_ws;
  int* counts = (int*)ws;                                   // 32 B
  int* list   = (int*)(ws + 1024);                          // 256 KB
  unsigned short* xb  = (unsigned short*)(ws + (1 << 20));  // [1,17) MB

  bool overlap = ws_size >= (size_t)210 * 1024 * 1024;
  unsigned short* W1T, *W2T, *H;
  if (overlap) {
    W1T = (unsigned short*)(ws + ((size_t)17  << 20));  // [17,81)
    W2T = (unsigned short*)(ws + ((size_t)81  << 20));  // [81,145)
    H   = (unsigned short*)(ws + ((size_t)145 << 20));  // [145,209)
  } else {
    W1T = (unsigned short*)(ws + ((size_t)17 << 20));   // [17,81) reused
    W2T = W1T;
    H   = (unsigned short*)(ws + ((size_t)81 << 20));   // [81,145)
  }

  hipMemsetAsync(counts, 0, NT * sizeof(int), stream);
  hipMemsetAsync(out, 0, (size_t)out_size * sizeof(float), stream);

  // launch 1: transpose W1 (z 0..7) + route (z 8..9)
  prep_kernel<<<dim3(64, 16, 10), 256, 0, stream>>>(
      x, pe, pwp, cwp, psig, csig, counts, list, xb, W1, W1T);

  // launch 2: gemm1 (z 0..7) + fused transpose W2 (z 8..15, overlap path only)
  gemm1_kernel<<<dim3(DH / BN, NTOK / BM, overlap ? 16 : 8), 256, 0, stream>>>(
      xb, W1T, b1, counts, list, H, W2, overlap ? W2T : nullptr);
  if (!overlap)
    t2_kernel<<<dim3(16, 64, 8), 256, 0, stream>>>(W2, W2T);

  // launch 3: gemm2 split-K x2
  gemm2_kernel<<<dim3(DC / BN, NTOK / BM, 16), 256, 0, stream>>>(
      H, W2T, b2, counts, list, out);
}